// Round 1
// baseline (966.465 us; speedup 1.0000x reference)
//
#include <hip/hip_runtime.h>
#include <math.h>

// Shapes: B=2, D=64, L=512, H=1024
// One fused cooperative kernel, 256 blocks x 256 threads (1 block/CU).
// Phase 1 (proj): unchanged — block (bd = blk>>1, h-half = blk&1) computes pX[bd, h-half].
// Phase 2 (recur): NO per-step grid barrier. State words are 8-byte {seq,value} entries
//   written with single relaxed agent-scope 8B atomic stores (tag+value single-copy atomic).
//   Consumers spin on the tags of exactly the entries they need (tag == d), collapsing the
//   old 5-6 serial MALL round trips/step (drain, flag, agg-poll, rel, rel-poll, re-load)
//   into ~1. Double-buffer by step parity; seq tag makes buffer reuse provably race-free.
//
// ws layout (floats):
//   [0,256)          flags (uint, 1/block)     -- used once (phase1->2 barrier)
//   [256]            rel (uint)                (pad to 320)
//   [320, 8512)      stC2: u64[2][2][1024] tagged state  (32 KB)
//   [8512, 16704)    stH2: u64[2][2][1024]               (32 KB)
//   [16704, ...)     pF (131072), pI, pO
// memset: first 16704 floats (65 KB) only.

#define NBLK 256
typedef unsigned long long u64;

__device__ __forceinline__ float sigf(float x)   { return 1.0f / (1.0f + __expf(-x)); }
__device__ __forceinline__ float geluf(float x)  { return 0.5f * x * (1.0f + erff(x * 0.70710678118654752f)); }
__device__ __forceinline__ float clampf(float x, float lo, float hi) { return fminf(fmaxf(x, lo), hi); }

__device__ __forceinline__ void astf(float* p, float v) {
    __hip_atomic_store(p, v, __ATOMIC_RELAXED, __HIP_MEMORY_SCOPE_AGENT);
}
__device__ __forceinline__ float aldf(const float* p) {
    return __hip_atomic_load(p, __ATOMIC_RELAXED, __HIP_MEMORY_SCOPE_AGENT);
}
__device__ __forceinline__ void astu(unsigned* p, unsigned v) {
    __hip_atomic_store(p, v, __ATOMIC_RELAXED, __HIP_MEMORY_SCOPE_AGENT);
}
__device__ __forceinline__ unsigned aldu(const unsigned* p) {
    return __hip_atomic_load(p, __ATOMIC_RELAXED, __HIP_MEMORY_SCOPE_AGENT);
}
__device__ __forceinline__ void ast64(u64* p, u64 v) {
    __hip_atomic_store(p, v, __ATOMIC_RELAXED, __HIP_MEMORY_SCOPE_AGENT);
}
__device__ __forceinline__ u64 ald64(const u64* p) {
    return __hip_atomic_load(p, __ATOMIC_RELAXED, __HIP_MEMORY_SCOPE_AGENT);
}

// Grid barrier (used ONCE, phase1 -> phase2): stores drained by leading __syncthreads.
__device__ __forceinline__ void gridbar(unsigned tgt, unsigned* flags, unsigned* rel,
                                        int blk, int t) {
    __syncthreads();
    if (t == 0) astu(&flags[blk], tgt);
    if (blk == 0) {
        if (t < 64) {
            for (;;) {
                unsigned a = aldu(&flags[t]);
                unsigned b = aldu(&flags[t + 64]);
                unsigned c = aldu(&flags[t + 128]);
                unsigned d = aldu(&flags[t + 192]);
                int ok = (a >= tgt) && (b >= tgt) && (c >= tgt) && (d >= tgt);
                if (__all(ok)) break;
                __builtin_amdgcn_s_sleep(1);
            }
            if (t == 0) astu(rel, tgt);
        }
    } else if (t == 0) {
        while (aldu(rel) < tgt) __builtin_amdgcn_s_sleep(2);
    }
    __syncthreads();
}

__global__ __launch_bounds__(256, 1) void fused_kernel(
    const float* __restrict__ trans, const int* __restrict__ mask,
    const float* __restrict__ Wf, const float* __restrict__ bf,
    const float* __restrict__ Wi, const float* __restrict__ bi,
    const float* __restrict__ Wg, const float* __restrict__ bg,
    const float* __restrict__ Wo, const float* __restrict__ bo,
    const float* __restrict__ Wp, const float* __restrict__ bp,
    const float* __restrict__ tF, const float* __restrict__ tI, const float* __restrict__ tO,
    const float* __restrict__ c_gamma, const float* __restrict__ c_beta,
    const float* __restrict__ h_gamma, const float* __restrict__ h_beta,
    float* __restrict__ ws, float* __restrict__ out)
{
    const int t    = threadIdx.x;
    const int lane = t & 63;
    const int wv   = t >> 6;
    const int blk  = blockIdx.x;
    const int hrow = (blk << 2) + wv;

    unsigned* flags = (unsigned*)ws;
    unsigned* rel   = flags + 256;
    u64* stC2 = (u64*)(ws + 320);      // [2 parity][2 batch][1024] tagged {seq,val}
    u64* stH2 = (u64*)(ws + 8512);
    float* pF  = ws + 16704;
    float* pI  = pF + 131072;
    float* pO  = pI + 131072;

    __shared__ float smem[2][4][1024];   // parity-double-buffered: proj scratch / normalized state
    __shared__ float red[2][4][8];

    // ---- register-resident weight rows (issued early; latency overlaps proj) ----
    float4 wfr[4], wir[4], wgr[4], wor[4], wpr[4];
    {
        const float4* rf = (const float4*)(Wf + (size_t)hrow * 1024);
        const float4* ri = (const float4*)(Wi + (size_t)hrow * 1024);
        const float4* rg = (const float4*)(Wg + (size_t)hrow * 1024);
        const float4* ro = (const float4*)(Wo + (size_t)hrow * 1024);
        const float4* rp = (const float4*)(Wp + (size_t)hrow * 1024);
        #pragma unroll
        for (int q = 0; q < 4; ++q) {
            const int k4 = lane + 64 * q;
            wfr[q] = rf[k4]; wir[q] = ri[k4]; wgr[q] = rg[k4];
            wor[q] = ro[k4]; wpr[q] = rp[k4];
        }
    }
    const float bfv = bf[hrow], biv = bi[hrow], bgv = bg[hrow], bov = bo[hrow], bpv = bp[hrow];

    // ================= Phase 1: projections =================
    {
        float* sF = &smem[0][0][0];     // 512
        float* sI = &smem[0][0][512];   // 512
        float* sO = &smem[0][1][0];     // 512
        sF[t] = tF[t]; sF[t + 256] = tF[t + 256];
        sI[t] = tI[t]; sI[t + 256] = tI[t + 256];
        sO[t] = tO[t]; sO[t + 256] = tO[t + 256];
        __syncthreads();

        const int bd = blk >> 1;
        const int h0 = (blk & 1) * 512;
        const int s  = t & 127;
        const int g  = t >> 7;
        const float4* tr = (const float4*)trans + (size_t)bd * 512 * 256 + (h0 >> 2) + s;

        float4 aF = make_float4(0.f,0.f,0.f,0.f);
        float4 aI = make_float4(0.f,0.f,0.f,0.f);
        float4 aO = make_float4(0.f,0.f,0.f,0.f);
        #pragma unroll 8
        for (int li = 0; li < 256; ++li) {
            const int l = g + 2 * li;
            float4 v = tr[(size_t)l * 256];
            const float wf = sF[l], wi = sI[l], wo = sO[l];
            aF.x = fmaf(v.x, wf, aF.x); aF.y = fmaf(v.y, wf, aF.y);
            aF.z = fmaf(v.z, wf, aF.z); aF.w = fmaf(v.w, wf, aF.w);
            aI.x = fmaf(v.x, wi, aI.x); aI.y = fmaf(v.y, wi, aI.y);
            aI.z = fmaf(v.z, wi, aI.z); aI.w = fmaf(v.w, wi, aI.w);
            aO.x = fmaf(v.x, wo, aO.x); aO.y = fmaf(v.y, wo, aO.y);
            aO.z = fmaf(v.z, wo, aO.z); aO.w = fmaf(v.w, wo, aO.w);
        }
        float4* cmb = (float4*)&smem[0][2][0];   // 384 float4
        if (g == 1) { cmb[s] = aF; cmb[128 + s] = aI; cmb[256 + s] = aO; }
        __syncthreads();
        if (g == 0) {
            const float4 bF = cmb[s], bI = cmb[128 + s], bO = cmb[256 + s];
            aF.x += bF.x; aF.y += bF.y; aF.z += bF.z; aF.w += bF.w;
            aI.x += bI.x; aI.y += bI.y; aI.z += bI.z; aI.w += bI.w;
            aO.x += bO.x; aO.y += bO.y; aO.z += bO.z; aO.w += bO.w;
            const int base = bd * 1024 + h0 + 4 * s;
            astf(&pF[base+0], aF.x); astf(&pF[base+1], aF.y);
            astf(&pF[base+2], aF.z); astf(&pF[base+3], aF.w);
            astf(&pI[base+0], aI.x); astf(&pI[base+1], aI.y);
            astf(&pI[base+2], aI.z); astf(&pI[base+3], aI.w);
            astf(&pO[base+0], aO.x); astf(&pO[base+1], aO.y);
            astf(&pO[base+2], aO.z); astf(&pO[base+3], aO.w);
        }
    }
    gridbar(1u, flags, rel, blk, t);

    // ================= Phase 2: recurrence (tag-spun state, no grid barrier) =================
    float cgv[4], cbv[4], hgv[4], hbv[4];
    #pragma unroll
    for (int j = 0; j < 4; ++j) {
        const int e = t + 256 * j;
        cgv[j] = c_gamma[e]; cbv[j] = c_beta[e];
        hgv[j] = h_gamma[e]; hbv[j] = h_beta[e];
    }

    for (int d = 0; d < 64; ++d) {
        const int par = d & 1;
        const u64* cc2 = stC2 + par * 2048;
        const u64* hc2 = stH2 + par * 2048;
        u64* cn2 = stC2 + (par ^ 1) * 2048;
        u64* hn2 = stH2 + (par ^ 1) * 2048;
        float (*sm)[1024] = smem[par];
        float (*rd)[8]    = red[par];

        // prefetch this step's projection scalars (latency hides under the spin)
        float pfv = 0.f, piv = 0.f, pov = 0.f;
        if (lane < 2) {
            const int pidx = (lane * 64 + d) * 1024 + hrow;
            pfv = aldf(&pF[pidx]); piv = aldf(&pI[pidx]); pov = aldf(&pO[pidx]);
        }

        // ---- per-thread spin: load {seq,val} entries, proceed when all tags == d ----
        u64 vc0[4], vc1[4], vh0[4], vh1[4];
        u64 vco = 0, vho = 0;              // lane<2: this wave's own old c/h (for gate update)
        const unsigned dtag = (unsigned)d;
        for (;;) {
            #pragma unroll
            for (int j = 0; j < 4; ++j) {
                const int e = t + 256 * j;
                vc0[j] = ald64(cc2 + e);        vc1[j] = ald64(cc2 + 1024 + e);
                vh0[j] = ald64(hc2 + e);        vh1[j] = ald64(hc2 + 1024 + e);
            }
            bool ok = true;
            #pragma unroll
            for (int j = 0; j < 4; ++j) {
                ok = ok && ((unsigned)(vc0[j] >> 32) == dtag) && ((unsigned)(vc1[j] >> 32) == dtag)
                        && ((unsigned)(vh0[j] >> 32) == dtag) && ((unsigned)(vh1[j] >> 32) == dtag);
            }
            if (lane < 2) {
                vco = ald64(cc2 + lane * 1024 + hrow);
                vho = ald64(hc2 + lane * 1024 + hrow);
                ok = ok && ((unsigned)(vco >> 32) == dtag) && ((unsigned)(vho >> 32) == dtag);
            }
            if (ok) break;
            __builtin_amdgcn_s_sleep(1);
        }

        // ---- unpack + LN stats ----
        float cv0[4], cv1[4], hv0[4], hv1[4];
        float s0=0,s1=0,s2=0,s3=0,s4=0,s5=0,s6=0,s7=0;
        #pragma unroll
        for (int j = 0; j < 4; ++j) {
            cv0[j] = __uint_as_float((unsigned)vc0[j]);
            cv1[j] = __uint_as_float((unsigned)vc1[j]);
            hv0[j] = __uint_as_float((unsigned)vh0[j]);
            hv1[j] = __uint_as_float((unsigned)vh1[j]);
            s0 += cv0[j]; s1 += cv0[j]*cv0[j];
            s2 += cv1[j]; s3 += cv1[j]*cv1[j];
            s4 += hv0[j]; s5 += hv0[j]*hv0[j];
            s6 += hv1[j]; s7 += hv1[j]*hv1[j];
        }
        #pragma unroll
        for (int off = 32; off; off >>= 1) {
            s0 += __shfl_xor(s0, off); s1 += __shfl_xor(s1, off);
            s2 += __shfl_xor(s2, off); s3 += __shfl_xor(s3, off);
            s4 += __shfl_xor(s4, off); s5 += __shfl_xor(s5, off);
            s6 += __shfl_xor(s6, off); s7 += __shfl_xor(s7, off);
        }
        if (lane == 0) {
            rd[wv][0]=s0; rd[wv][1]=s1; rd[wv][2]=s2; rd[wv][3]=s3;
            rd[wv][4]=s4; rd[wv][5]=s5; rd[wv][6]=s6; rd[wv][7]=s7;
        }
        __syncthreads();
        const float tc0 = rd[0][0]+rd[1][0]+rd[2][0]+rd[3][0];
        const float qc0 = rd[0][1]+rd[1][1]+rd[2][1]+rd[3][1];
        const float tc1 = rd[0][2]+rd[1][2]+rd[2][2]+rd[3][2];
        const float qc1 = rd[0][3]+rd[1][3]+rd[2][3]+rd[3][3];
        const float th0 = rd[0][4]+rd[1][4]+rd[2][4]+rd[3][4];
        const float qh0 = rd[0][5]+rd[1][5]+rd[2][5]+rd[3][5];
        const float th1 = rd[0][6]+rd[1][6]+rd[2][6]+rd[3][6];
        const float qh1 = rd[0][7]+rd[1][7]+rd[2][7]+rd[3][7];
        const float inv = 1.0f / 1024.0f;
        const float mc0 = tc0*inv, rc0 = rsqrtf(qc0*inv - mc0*mc0 + 1e-5f);
        const float mc1 = tc1*inv, rc1 = rsqrtf(qc1*inv - mc1*mc1 + 1e-5f);
        const float mh0 = th0*inv, rh0 = rsqrtf(qh0*inv - mh0*mh0 + 1e-5f);
        const float mh1 = th1*inv, rh1 = rsqrtf(qh1*inv - mh1*mh1 + 1e-5f);

        #pragma unroll
        for (int j = 0; j < 4; ++j) {
            const int e = t + 256 * j;
            sm[0][e] = (hv0[j]-mh0)*rh0*hgv[j] + hbv[j];
            sm[1][e] = (hv1[j]-mh1)*rh1*hgv[j] + hbv[j];
            sm[2][e] = (cv0[j]-mc0)*rc0*cgv[j] + cbv[j];
            sm[3][e] = (cv1[j]-mc1)*rc1*cgv[j] + cbv[j];
        }
        __syncthreads();

        // ---- 10 dot products (5 matrices x b=0,1) for this wave's row ----
        float zf0=0,zf1=0,zi0=0,zi1=0,zg0=0,zg1=0,zo0=0,zo1=0,zp0=0,zp1=0;
        #pragma unroll
        for (int q = 0; q < 4; ++q) {
            const int k4 = lane + 64 * q;
            const float4 n0 = ((const float4*)sm[0])[k4];
            const float4 n1 = ((const float4*)sm[1])[k4];
            const float4 m0 = ((const float4*)sm[2])[k4];
            const float4 m1 = ((const float4*)sm[3])[k4];
            zf0 += wfr[q].x*n0.x + wfr[q].y*n0.y + wfr[q].z*n0.z + wfr[q].w*n0.w;
            zf1 += wfr[q].x*n1.x + wfr[q].y*n1.y + wfr[q].z*n1.z + wfr[q].w*n1.w;
            zi0 += wir[q].x*n0.x + wir[q].y*n0.y + wir[q].z*n0.z + wir[q].w*n0.w;
            zi1 += wir[q].x*n1.x + wir[q].y*n1.y + wir[q].z*n1.z + wir[q].w*n1.w;
            zg0 += wgr[q].x*n0.x + wgr[q].y*n0.y + wgr[q].z*n0.z + wgr[q].w*n0.w;
            zg1 += wgr[q].x*n1.x + wgr[q].y*n1.y + wgr[q].z*n1.z + wgr[q].w*n1.w;
            zo0 += wor[q].x*n0.x + wor[q].y*n0.y + wor[q].z*n0.z + wor[q].w*n0.w;
            zo1 += wor[q].x*n1.x + wor[q].y*n1.y + wor[q].z*n1.z + wor[q].w*n1.w;
            zp0 += wpr[q].x*m0.x + wpr[q].y*m0.y + wpr[q].z*m0.z + wpr[q].w*m0.w;
            zp1 += wpr[q].x*m1.x + wpr[q].y*m1.y + wpr[q].z*m1.z + wpr[q].w*m1.w;
        }
        #pragma unroll
        for (int off = 32; off; off >>= 1) {
            zf0 += __shfl_xor(zf0, off); zf1 += __shfl_xor(zf1, off);
            zi0 += __shfl_xor(zi0, off); zi1 += __shfl_xor(zi1, off);
            zg0 += __shfl_xor(zg0, off); zg1 += __shfl_xor(zg1, off);
            zo0 += __shfl_xor(zo0, off); zo1 += __shfl_xor(zo1, off);
            zp0 += __shfl_xor(zp0, off); zp1 += __shfl_xor(zp1, off);
        }

        // ---- gates + state update: lane 0 -> b=0, lane 1 -> b=1 ----
        if (lane < 2) {
            const int b = lane;
            const float zf = b ? zf1 : zf0;
            const float zi = b ? zi1 : zi0;
            const float zg = b ? zg1 : zg0;
            const float zo = b ? zo1 : zo0;
            const float zp = b ? zp1 : zp0;
            const float f  = sigf(clampf(zf + bfv, -8.f, 8.f) + pfv);
            const float ig = sigf(clampf(zi + biv, -8.f, 8.f) + piv);
            const float g  = clampf(geluf(zg + bgv) + piv, -8.f, 8.f);
            const float o  = sigf(clampf(zo + bov, -8.f, 8.f) + pov);
            const float hp = clampf(geluf(zp + bpv), -8.f, 8.f);
            const float co = __uint_as_float((unsigned)vco);
            const float ho = __uint_as_float((unsigned)vho);
            float c2 = co * f + ig * g;
            float h2 = o * hp;
            if (mask[b * 64 + d] == 0) { c2 = co; h2 = ho; }
            c2 = clampf(c2, -10.f, 10.f);
            h2 = clampf(h2, -10.f, 10.f);
            if (d == 63) {
                out[b * 1024 + hrow] = h2;
            } else {
                const u64 tg = ((u64)(unsigned)(d + 1)) << 32;
                ast64(cn2 + b * 1024 + hrow, tg | (u64)__float_as_uint(c2));
                ast64(hn2 + b * 1024 + hrow, tg | (u64)__float_as_uint(h2));
            }
        }
        // no trailing barrier: next iteration's smem fill targets the other parity buffer,
        // and the seq-tag spin provides the cross-block ordering.
    }
}

extern "C" void kernel_launch(void* const* d_in, const int* in_sizes, int n_in,
                              void* d_out, int out_size, void* d_ws, size_t ws_size,
                              hipStream_t stream)
{
    const float* trans = (const float*)d_in[0];
    const int*   mask  = (const int*)d_in[1];
    const float* Wf = (const float*)d_in[2];  const float* bf = (const float*)d_in[3];
    const float* Wi = (const float*)d_in[4];  const float* bi = (const float*)d_in[5];
    const float* Wg = (const float*)d_in[6];  const float* bg = (const float*)d_in[7];
    const float* Wo = (const float*)d_in[8];  const float* bo = (const float*)d_in[9];
    const float* Wp = (const float*)d_in[10]; const float* bp = (const float*)d_in[11];
    const float* tF = (const float*)d_in[12];
    const float* tI = (const float*)d_in[13];
    const float* tO = (const float*)d_in[14];
    const float* c_gamma = (const float*)d_in[15];
    const float* c_beta  = (const float*)d_in[16];
    const float* h_gamma = (const float*)d_in[17];
    const float* h_beta  = (const float*)d_in[18];

    float* ws  = (float*)d_ws;
    float* out = (float*)d_out;

    // zero flags + rel + both parities of tagged c/h state (65 KB)
    hipMemsetAsync(d_ws, 0, 16704u * sizeof(float), stream);

    void* args[] = { (void*)&trans, (void*)&mask,
                     (void*)&Wf, (void*)&bf, (void*)&Wi, (void*)&bi,
                     (void*)&Wg, (void*)&bg, (void*)&Wo, (void*)&bo,
                     (void*)&Wp, (void*)&bp,
                     (void*)&tF, (void*)&tI, (void*)&tO,
                     (void*)&c_gamma, (void*)&c_beta, (void*)&h_gamma, (void*)&h_beta,
                     (void*)&ws, (void*)&out };
    hipLaunchCooperativeKernel((void*)fused_kernel, dim3(256), dim3(256), args, 0, stream);
}

// Round 3
// 895.684 us; speedup vs baseline: 1.0790x; 1.0790x over previous
//
#include <hip/hip_runtime.h>
#include <math.h>

// Shapes: B=2, D=64, L=512, H=1024
// One fused cooperative kernel, 256 blocks x 256 threads (1 block/CU).
// Phase 1 (proj): block (bd = blk>>1, h-half = blk&1) computes pX[bd, h-half] for X in {F,I,O}.
// Phase 2 (recur): per-step sync = per-block flags + DISTRIBUTED poll (each block's wave 0
//   polls all 256 flags itself). No central aggregator, no release broadcast.
//   A dedicated distributed wait for phase-1 completion sits BEFORE the loop so that the
//   iteration-0 projection prefetch cannot race other blocks' phase-1 stores (round-2 bug).
//   LN affine is folded into the register-resident weight rows (w *= gamma; per-row scalars
//   s = sum(W*gamma), bb = sum(W*beta)), so the 10 dot products run on RAW state:
//   z = r*(dot_raw - m*s) + bb. The stats reduction no longer gates the dots, and the
//   normalized-smem pass + one barrier are gone. Own-row c/h persist in lane<2 registers.
//
// ws layout (floats):
//   [0,256)        flags (uint, 1/block)   (pad to 320)
//   [320, 4416)    stC (2 parities x 2 x 1024)
//   [4416, 8512)   stH
//   [8512, 139584) pF    [139584, 270656) pI    [270656, 401728) pO
// memset: first 8512 floats (34 KB) only.

#define NBLK 256

__device__ __forceinline__ float sigf(float x)   { return 1.0f / (1.0f + __expf(-x)); }
__device__ __forceinline__ float geluf(float x)  { return 0.5f * x * (1.0f + erff(x * 0.70710678118654752f)); }
__device__ __forceinline__ float clampf(float x, float lo, float hi) { return fminf(fmaxf(x, lo), hi); }

__device__ __forceinline__ void astf(float* p, float v) {
    __hip_atomic_store(p, v, __ATOMIC_RELAXED, __HIP_MEMORY_SCOPE_AGENT);
}
__device__ __forceinline__ float aldf(const float* p) {
    return __hip_atomic_load(p, __ATOMIC_RELAXED, __HIP_MEMORY_SCOPE_AGENT);
}
__device__ __forceinline__ void astu(unsigned* p, unsigned v) {
    __hip_atomic_store(p, v, __ATOMIC_RELAXED, __HIP_MEMORY_SCOPE_AGENT);
}
__device__ __forceinline__ unsigned aldu(const unsigned* p) {
    return __hip_atomic_load(p, __ATOMIC_RELAXED, __HIP_MEMORY_SCOPE_AGENT);
}

__global__ __launch_bounds__(256, 1) void fused_kernel(
    const float* __restrict__ trans, const int* __restrict__ mask,
    const float* __restrict__ Wf, const float* __restrict__ bf,
    const float* __restrict__ Wi, const float* __restrict__ bi,
    const float* __restrict__ Wg, const float* __restrict__ bg,
    const float* __restrict__ Wo, const float* __restrict__ bo,
    const float* __restrict__ Wp, const float* __restrict__ bp,
    const float* __restrict__ tF, const float* __restrict__ tI, const float* __restrict__ tO,
    const float* __restrict__ c_gamma, const float* __restrict__ c_beta,
    const float* __restrict__ h_gamma, const float* __restrict__ h_beta,
    float* __restrict__ ws, float* __restrict__ out)
{
    const int t    = threadIdx.x;
    const int lane = t & 63;
    const int wv   = t >> 6;
    const int blk  = blockIdx.x;
    const int hrow = (blk << 2) + wv;

    unsigned* flags = (unsigned*)ws;
    float* stC = ws + 320;
    float* stH = ws + 4416;
    float* pF  = ws + 8512;
    float* pI  = pF + 131072;
    float* pO  = pI + 131072;

    __shared__ float smem[2][4][1024];   // parity-buffered raw-state exchange (+ proj scratch)
    __shared__ float red[2][4][8];

    // ---- register-resident weight rows (issued early; latency overlaps proj) ----
    float4 wfr[4], wir[4], wgr[4], wor[4], wpr[4];
    {
        const float4* rf = (const float4*)(Wf + (size_t)hrow * 1024);
        const float4* ri = (const float4*)(Wi + (size_t)hrow * 1024);
        const float4* rg = (const float4*)(Wg + (size_t)hrow * 1024);
        const float4* ro = (const float4*)(Wo + (size_t)hrow * 1024);
        const float4* rp = (const float4*)(Wp + (size_t)hrow * 1024);
        #pragma unroll
        for (int q = 0; q < 4; ++q) {
            const int k4 = lane + 64 * q;
            wfr[q] = rf[k4]; wir[q] = ri[k4]; wgr[q] = rg[k4];
            wor[q] = ro[k4]; wpr[q] = rp[k4];
        }
    }
    const float bfv = bf[hrow], biv = bi[hrow], bgv = bg[hrow], bov = bo[hrow], bpv = bp[hrow];

    // ================= Phase 1: projections =================
    {
        float* sF = &smem[0][0][0];     // 512
        float* sI = &smem[0][0][512];   // 512
        float* sO = &smem[0][1][0];     // 512
        sF[t] = tF[t]; sF[t + 256] = tF[t + 256];
        sI[t] = tI[t]; sI[t + 256] = tI[t + 256];
        sO[t] = tO[t]; sO[t + 256] = tO[t + 256];
        __syncthreads();

        const int bd = blk >> 1;
        const int h0 = (blk & 1) * 512;
        const int s  = t & 127;          // float4 slot within the 512-wide half
        const int g  = t >> 7;           // l-parity group
        const float4* tr = (const float4*)trans + (size_t)bd * 512 * 256 + (h0 >> 2) + s;

        float4 aF = make_float4(0.f,0.f,0.f,0.f);
        float4 aI = make_float4(0.f,0.f,0.f,0.f);
        float4 aO = make_float4(0.f,0.f,0.f,0.f);
        #pragma unroll 8
        for (int li = 0; li < 256; ++li) {
            const int l = g + 2 * li;
            float4 v = tr[(size_t)l * 256];
            const float wf = sF[l], wi = sI[l], wo = sO[l];
            aF.x = fmaf(v.x, wf, aF.x); aF.y = fmaf(v.y, wf, aF.y);
            aF.z = fmaf(v.z, wf, aF.z); aF.w = fmaf(v.w, wf, aF.w);
            aI.x = fmaf(v.x, wi, aI.x); aI.y = fmaf(v.y, wi, aI.y);
            aI.z = fmaf(v.z, wi, aI.z); aI.w = fmaf(v.w, wi, aI.w);
            aO.x = fmaf(v.x, wo, aO.x); aO.y = fmaf(v.y, wo, aO.y);
            aO.z = fmaf(v.z, wo, aO.z); aO.w = fmaf(v.w, wo, aO.w);
        }
        float4* cmb = (float4*)&smem[0][2][0];   // 384 float4
        if (g == 1) { cmb[s] = aF; cmb[128 + s] = aI; cmb[256 + s] = aO; }
        __syncthreads();
        if (g == 0) {
            const float4 bF = cmb[s], bI = cmb[128 + s], bO = cmb[256 + s];
            aF.x += bF.x; aF.y += bF.y; aF.z += bF.z; aF.w += bF.w;
            aI.x += bI.x; aI.y += bI.y; aI.z += bI.z; aI.w += bI.w;
            aO.x += bO.x; aO.y += bO.y; aO.z += bO.z; aO.w += bO.w;
            const int base = bd * 1024 + h0 + 4 * s;
            astf(&pF[base+0], aF.x); astf(&pF[base+1], aF.y);
            astf(&pF[base+2], aF.z); astf(&pF[base+3], aF.w);
            astf(&pI[base+0], aI.x); astf(&pI[base+1], aI.y);
            astf(&pI[base+2], aI.z); astf(&pI[base+3], aI.w);
            astf(&pO[base+0], aO.x); astf(&pO[base+1], aO.y);
            astf(&pO[base+2], aO.z); astf(&pO[base+3], aO.w);
        }
    }
    __syncthreads();                     // drain proj stores (vmcnt(0) before s_barrier)
    if (t == 0) astu(&flags[blk], 1u);

    // ---- fold LN affine into weights; per-row scalars (overlaps other blocks' proj) ----
    float sfv, siv, sgv, sov, spv, bfb, bib, bgb, bob, bpb;
    {
        float4 gh4[4], bh4[4], gc4[4], bc4[4];
        const float4* Gh = (const float4*)h_gamma;
        const float4* Bh = (const float4*)h_beta;
        const float4* Gc = (const float4*)c_gamma;
        const float4* Bc = (const float4*)c_beta;
        #pragma unroll
        for (int q = 0; q < 4; ++q) {
            const int k4 = lane + 64 * q;
            gh4[q] = Gh[k4]; bh4[q] = Bh[k4]; gc4[q] = Gc[k4]; bc4[q] = Bc[k4];
        }
        bfb = bib = bgb = bob = bpb = 0.f;
        #pragma unroll
        for (int q = 0; q < 4; ++q) {
            bfb += wfr[q].x*bh4[q].x + wfr[q].y*bh4[q].y + wfr[q].z*bh4[q].z + wfr[q].w*bh4[q].w;
            bib += wir[q].x*bh4[q].x + wir[q].y*bh4[q].y + wir[q].z*bh4[q].z + wir[q].w*bh4[q].w;
            bgb += wgr[q].x*bh4[q].x + wgr[q].y*bh4[q].y + wgr[q].z*bh4[q].z + wgr[q].w*bh4[q].w;
            bob += wor[q].x*bh4[q].x + wor[q].y*bh4[q].y + wor[q].z*bh4[q].z + wor[q].w*bh4[q].w;
            bpb += wpr[q].x*bc4[q].x + wpr[q].y*bc4[q].y + wpr[q].z*bc4[q].z + wpr[q].w*bc4[q].w;
        }
        #pragma unroll
        for (int q = 0; q < 4; ++q) {
            wfr[q].x *= gh4[q].x; wfr[q].y *= gh4[q].y; wfr[q].z *= gh4[q].z; wfr[q].w *= gh4[q].w;
            wir[q].x *= gh4[q].x; wir[q].y *= gh4[q].y; wir[q].z *= gh4[q].z; wir[q].w *= gh4[q].w;
            wgr[q].x *= gh4[q].x; wgr[q].y *= gh4[q].y; wgr[q].z *= gh4[q].z; wgr[q].w *= gh4[q].w;
            wor[q].x *= gh4[q].x; wor[q].y *= gh4[q].y; wor[q].z *= gh4[q].z; wor[q].w *= gh4[q].w;
            wpr[q].x *= gc4[q].x; wpr[q].y *= gc4[q].y; wpr[q].z *= gc4[q].z; wpr[q].w *= gc4[q].w;
        }
        sfv = siv = sgv = sov = spv = 0.f;
        #pragma unroll
        for (int q = 0; q < 4; ++q) {
            sfv += wfr[q].x + wfr[q].y + wfr[q].z + wfr[q].w;
            siv += wir[q].x + wir[q].y + wir[q].z + wir[q].w;
            sgv += wgr[q].x + wgr[q].y + wgr[q].z + wgr[q].w;
            sov += wor[q].x + wor[q].y + wor[q].z + wor[q].w;
            spv += wpr[q].x + wpr[q].y + wpr[q].z + wpr[q].w;
        }
        #pragma unroll
        for (int off = 32; off; off >>= 1) {
            sfv += __shfl_xor(sfv, off); siv += __shfl_xor(siv, off);
            sgv += __shfl_xor(sgv, off); sov += __shfl_xor(sov, off);
            spv += __shfl_xor(spv, off);
            bfb += __shfl_xor(bfb, off); bib += __shfl_xor(bib, off);
            bgb += __shfl_xor(bgb, off); bob += __shfl_xor(bob, off);
            bpb += __shfl_xor(bpb, off);
        }
    }

    // ---- phase-1 completion wait (distributed): MUST precede the first proj prefetch.
    //      (round-2 bug: iteration-0 prefetch raced other blocks' phase-1 stores)
    if (wv == 0) {
        for (;;) {
            const unsigned a0 = aldu(&flags[lane]);
            const unsigned a1 = aldu(&flags[lane + 64]);
            const unsigned a2 = aldu(&flags[lane + 128]);
            const unsigned a3 = aldu(&flags[lane + 192]);
            const int ok = (a0 >= 1u) && (a1 >= 1u) && (a2 >= 1u) && (a3 >= 1u);
            if (__all(ok)) break;
            __builtin_amdgcn_s_sleep(1);
        }
    }
    __syncthreads();

    // ================= Phase 2: recurrence =================
    float c_prev = 0.f, h_prev = 0.f;    // lane<2: own row's state, register-resident

    for (int d = 0; d < 64; ++d) {
        const int par = d & 1;
        const float* cc = stC + par * 2048;
        const float* hc = stH + par * 2048;
        float* cn = stC + (par ^ 1) * 2048;
        float* hn = stH + (par ^ 1) * 2048;
        float (*sm)[1024] = smem[par];
        float (*rd)[8]    = red[par];

        // prefetch this step's projection scalars + mask (latency hides under poll)
        // safe for all d: the pre-loop wait (d=0) / previous iteration's poll (d>=1)
        // guarantee flags >= 1 grid-wide, i.e. phase 1 fully stored.
        float pfv = 0.f, piv = 0.f, pov = 0.f;
        int mv = 1;
        if (lane < 2) {
            const int pidx = (lane * 64 + d) * 1024 + hrow;
            pfv = aldf(&pF[pidx]); piv = aldf(&pI[pidx]); pov = aldf(&pO[pidx]);
            mv = mask[lane * 64 + d];
        }

        // ---- distributed poll: wave 0 checks all 256 per-block flags directly ----
        if (wv == 0) {
            const unsigned tgt = (unsigned)(d + 1);
            for (;;) {
                const unsigned a0 = aldu(&flags[lane]);
                const unsigned a1 = aldu(&flags[lane + 64]);
                const unsigned a2 = aldu(&flags[lane + 128]);
                const unsigned a3 = aldu(&flags[lane + 192]);
                const int ok = (a0 >= tgt) && (a1 >= tgt) && (a2 >= tgt) && (a3 >= tgt);
                if (__all(ok)) break;
                __builtin_amdgcn_s_sleep(1);
            }
        }
        __syncthreads();

        // ---- state read (agent scope) ----
        float cv0[4], cv1[4], hv0[4], hv1[4];
        #pragma unroll
        for (int j = 0; j < 4; ++j) {
            const int e = t + 256 * j;
            cv0[j] = aldf(cc + e);        cv1[j] = aldf(cc + 1024 + e);
            hv0[j] = aldf(hc + e);        hv1[j] = aldf(hc + 1024 + e);
        }
        // raw state -> smem; LN stats partials from registers
        float s0=0,s1=0,s2=0,s3=0,s4=0,s5=0,s6=0,s7=0;
        #pragma unroll
        for (int j = 0; j < 4; ++j) {
            const int e = t + 256 * j;
            sm[0][e] = hv0[j]; sm[1][e] = hv1[j];
            sm[2][e] = cv0[j]; sm[3][e] = cv1[j];
            s0 += cv0[j]; s1 += cv0[j]*cv0[j];
            s2 += cv1[j]; s3 += cv1[j]*cv1[j];
            s4 += hv0[j]; s5 += hv0[j]*hv0[j];
            s6 += hv1[j]; s7 += hv1[j]*hv1[j];
        }
        #pragma unroll
        for (int off = 32; off; off >>= 1) {
            s0 += __shfl_xor(s0, off); s1 += __shfl_xor(s1, off);
            s2 += __shfl_xor(s2, off); s3 += __shfl_xor(s3, off);
            s4 += __shfl_xor(s4, off); s5 += __shfl_xor(s5, off);
            s6 += __shfl_xor(s6, off); s7 += __shfl_xor(s7, off);
        }
        if (lane == 0) {
            rd[wv][0]=s0; rd[wv][1]=s1; rd[wv][2]=s2; rd[wv][3]=s3;
            rd[wv][4]=s4; rd[wv][5]=s5; rd[wv][6]=s6; rd[wv][7]=s7;
        }
        __syncthreads();

        const float tc0 = rd[0][0]+rd[1][0]+rd[2][0]+rd[3][0];
        const float qc0 = rd[0][1]+rd[1][1]+rd[2][1]+rd[3][1];
        const float tc1 = rd[0][2]+rd[1][2]+rd[2][2]+rd[3][2];
        const float qc1 = rd[0][3]+rd[1][3]+rd[2][3]+rd[3][3];
        const float th0 = rd[0][4]+rd[1][4]+rd[2][4]+rd[3][4];
        const float qh0 = rd[0][5]+rd[1][5]+rd[2][5]+rd[3][5];
        const float th1 = rd[0][6]+rd[1][6]+rd[2][6]+rd[3][6];
        const float qh1 = rd[0][7]+rd[1][7]+rd[2][7]+rd[3][7];
        const float inv = 1.0f / 1024.0f;
        const float mc0 = tc0*inv, rc0 = rsqrtf(qc0*inv - mc0*mc0 + 1e-5f);
        const float mc1 = tc1*inv, rc1 = rsqrtf(qc1*inv - mc1*mc1 + 1e-5f);
        const float mh0 = th0*inv, rh0 = rsqrtf(qh0*inv - mh0*mh0 + 1e-5f);
        const float mh1 = th1*inv, rh1 = rsqrtf(qh1*inv - mh1*mh1 + 1e-5f);

        // ---- 10 dot products on RAW state (gamma folded into weights) ----
        float zf0=0,zf1=0,zi0=0,zi1=0,zg0=0,zg1=0,zo0=0,zo1=0,zp0=0,zp1=0;
        #pragma unroll
        for (int q = 0; q < 4; ++q) {
            const int k4 = lane + 64 * q;
            const float4 n0 = ((const float4*)sm[0])[k4];
            const float4 n1 = ((const float4*)sm[1])[k4];
            const float4 m0 = ((const float4*)sm[2])[k4];
            const float4 m1 = ((const float4*)sm[3])[k4];
            zf0 += wfr[q].x*n0.x + wfr[q].y*n0.y + wfr[q].z*n0.z + wfr[q].w*n0.w;
            zf1 += wfr[q].x*n1.x + wfr[q].y*n1.y + wfr[q].z*n1.z + wfr[q].w*n1.w;
            zi0 += wir[q].x*n0.x + wir[q].y*n0.y + wir[q].z*n0.z + wir[q].w*n0.w;
            zi1 += wir[q].x*n1.x + wir[q].y*n1.y + wir[q].z*n1.z + wir[q].w*n1.w;
            zg0 += wgr[q].x*n0.x + wgr[q].y*n0.y + wgr[q].z*n0.z + wgr[q].w*n0.w;
            zg1 += wgr[q].x*n1.x + wgr[q].y*n1.y + wgr[q].z*n1.z + wgr[q].w*n1.w;
            zo0 += wor[q].x*n0.x + wor[q].y*n0.y + wor[q].z*n0.z + wor[q].w*n0.w;
            zo1 += wor[q].x*n1.x + wor[q].y*n1.y + wor[q].z*n1.z + wor[q].w*n1.w;
            zp0 += wpr[q].x*m0.x + wpr[q].y*m0.y + wpr[q].z*m0.z + wpr[q].w*m0.w;
            zp1 += wpr[q].x*m1.x + wpr[q].y*m1.y + wpr[q].z*m1.z + wpr[q].w*m1.w;
        }
        #pragma unroll
        for (int off = 32; off; off >>= 1) {
            zf0 += __shfl_xor(zf0, off); zf1 += __shfl_xor(zf1, off);
            zi0 += __shfl_xor(zi0, off); zi1 += __shfl_xor(zi1, off);
            zg0 += __shfl_xor(zg0, off); zg1 += __shfl_xor(zg1, off);
            zo0 += __shfl_xor(zo0, off); zo1 += __shfl_xor(zo1, off);
            zp0 += __shfl_xor(zp0, off); zp1 += __shfl_xor(zp1, off);
        }

        // ---- finalize z (affine correction) + gates: lane 0 -> b=0, lane 1 -> b=1 ----
        if (lane < 2) {
            const int b = lane;
            const float mh = b ? mh1 : mh0, rh = b ? rh1 : rh0;
            const float mc = b ? mc1 : mc0, rc = b ? rc1 : rc0;
            const float zf = rh * ((b ? zf1 : zf0) - mh * sfv) + bfb;
            const float zi = rh * ((b ? zi1 : zi0) - mh * siv) + bib;
            const float zg = rh * ((b ? zg1 : zg0) - mh * sgv) + bgb;
            const float zo = rh * ((b ? zo1 : zo0) - mh * sov) + bob;
            const float zp = rc * ((b ? zp1 : zp0) - mc * spv) + bpb;
            const float f  = sigf(clampf(zf + bfv, -8.f, 8.f) + pfv);
            const float ig = sigf(clampf(zi + biv, -8.f, 8.f) + piv);
            const float g  = clampf(geluf(zg + bgv) + piv, -8.f, 8.f);
            const float o  = sigf(clampf(zo + bov, -8.f, 8.f) + pov);
            const float hp = clampf(geluf(zp + bpv), -8.f, 8.f);
            float c2 = c_prev * f + ig * g;
            float h2 = o * hp;
            if (mv == 0) { c2 = c_prev; h2 = h_prev; }
            c2 = clampf(c2, -10.f, 10.f);
            h2 = clampf(h2, -10.f, 10.f);
            c_prev = c2; h_prev = h2;
            if (d == 63) {
                out[b * 1024 + hrow] = h2;
            } else {
                astf(cn + b * 1024 + hrow, c2);
                astf(hn + b * 1024 + hrow, h2);
            }
        }

        if (d == 63) break;
        __syncthreads();                         // drain state stores (vmcnt(0) before s_barrier)
        if (t == 0) astu(&flags[blk], (unsigned)(d + 2));
    }
}

extern "C" void kernel_launch(void* const* d_in, const int* in_sizes, int n_in,
                              void* d_out, int out_size, void* d_ws, size_t ws_size,
                              hipStream_t stream)
{
    const float* trans = (const float*)d_in[0];
    const int*   mask  = (const int*)d_in[1];
    const float* Wf = (const float*)d_in[2];  const float* bf = (const float*)d_in[3];
    const float* Wi = (const float*)d_in[4];  const float* bi = (const float*)d_in[5];
    const float* Wg = (const float*)d_in[6];  const float* bg = (const float*)d_in[7];
    const float* Wo = (const float*)d_in[8];  const float* bo = (const float*)d_in[9];
    const float* Wp = (const float*)d_in[10]; const float* bp = (const float*)d_in[11];
    const float* tF = (const float*)d_in[12];
    const float* tI = (const float*)d_in[13];
    const float* tO = (const float*)d_in[14];
    const float* c_gamma = (const float*)d_in[15];
    const float* c_beta  = (const float*)d_in[16];
    const float* h_gamma = (const float*)d_in[17];
    const float* h_beta  = (const float*)d_in[18];

    float* ws  = (float*)d_ws;
    float* out = (float*)d_out;

    // zero flags + initial c/h state only (34 KB)
    hipMemsetAsync(d_ws, 0, 8512u * sizeof(float), stream);

    void* args[] = { (void*)&trans, (void*)&mask,
                     (void*)&Wf, (void*)&bf, (void*)&Wi, (void*)&bi,
                     (void*)&Wg, (void*)&bg, (void*)&Wo, (void*)&bo,
                     (void*)&Wp, (void*)&bp,
                     (void*)&tF, (void*)&tI, (void*)&tO,
                     (void*)&c_gamma, (void*)&c_beta, (void*)&h_gamma, (void*)&h_beta,
                     (void*)&ws, (void*)&out };
    hipLaunchCooperativeKernel((void*)fused_kernel, dim3(256), dim3(256), args, 0, stream);
}

// Round 4
// 801.854 us; speedup vs baseline: 1.2053x; 1.1170x over previous
//
#include <hip/hip_runtime.h>
#include <math.h>

// Shapes: B=2, D=64, L=512, H=1024
// One fused cooperative kernel, 256 blocks x 256 threads (1 block/CU).
// Phase 1 (proj): block (bd = blk>>1, h-half = blk&1) computes pX[bd, h-half] for X in {F,I,O}.
// Phase 2 (recur): aggregator sync with REPLICATED release lines.
//   Evidence (r0=507 agg+1rel, r1=648 all-thread data spin, r3=562 distributed poll):
//   step time tracks per-hot-line contention, not hop count. So: flags stay cold (only the
//   aggregator reads them), and the release word is replicated across 16 private 64-B lines
//   (consumers poll rel[blk&15] -> ~16 readers/line; aggregator's 16 stores are pipelined).
//   LN affine folded into register-resident weight rows (dots run on RAW state, finalize is
//   z = r*(dot - m*s) + bb). Stats are PER-WAVE (each wave's dot registers span the full
//   1024-vector), removing the red[] LDS exchange entirely. Own-row c/h live in registers.
//
// ws layout (floats):
//   [0,256)        flags (uint, 1/block) — read only by aggregator
//   [256,512)      rel slots: 16 x (16-uint stride) = one 64-B line each
//   [512, 4608)    stC (2 parities x 2 x 1024)
//   [4608, 8704)   stH
//   [8704, 139776) pF   [139776, 270848) pI   [270848, 401920) pO
// memset: first 8704 floats (35 KB) only.

#define NBLK 256

__device__ __forceinline__ float sigf(float x)   { return 1.0f / (1.0f + __expf(-x)); }
__device__ __forceinline__ float geluf(float x)  { return 0.5f * x * (1.0f + erff(x * 0.70710678118654752f)); }
__device__ __forceinline__ float clampf(float x, float lo, float hi) { return fminf(fmaxf(x, lo), hi); }

__device__ __forceinline__ void astf(float* p, float v) {
    __hip_atomic_store(p, v, __ATOMIC_RELAXED, __HIP_MEMORY_SCOPE_AGENT);
}
__device__ __forceinline__ float aldf(const float* p) {
    return __hip_atomic_load(p, __ATOMIC_RELAXED, __HIP_MEMORY_SCOPE_AGENT);
}
__device__ __forceinline__ void astu(unsigned* p, unsigned v) {
    __hip_atomic_store(p, v, __ATOMIC_RELAXED, __HIP_MEMORY_SCOPE_AGENT);
}
__device__ __forceinline__ unsigned aldu(const unsigned* p) {
    return __hip_atomic_load(p, __ATOMIC_RELAXED, __HIP_MEMORY_SCOPE_AGENT);
}

__global__ __launch_bounds__(256, 1) void fused_kernel(
    const float* __restrict__ trans, const int* __restrict__ mask,
    const float* __restrict__ Wf, const float* __restrict__ bf,
    const float* __restrict__ Wi, const float* __restrict__ bi,
    const float* __restrict__ Wg, const float* __restrict__ bg,
    const float* __restrict__ Wo, const float* __restrict__ bo,
    const float* __restrict__ Wp, const float* __restrict__ bp,
    const float* __restrict__ tF, const float* __restrict__ tI, const float* __restrict__ tO,
    const float* __restrict__ c_gamma, const float* __restrict__ c_beta,
    const float* __restrict__ h_gamma, const float* __restrict__ h_beta,
    float* __restrict__ ws, float* __restrict__ out)
{
    const int t    = threadIdx.x;
    const int lane = t & 63;
    const int wv   = t >> 6;
    const int blk  = blockIdx.x;
    const int hrow = (blk << 2) + wv;

    unsigned* flags = (unsigned*)ws;          // [0,256)
    unsigned* rel   = flags + 256;            // 16 slots, stride 16 uints (64-B lines)
    float* stC = ws + 512;
    float* stH = ws + 4608;
    float* pF  = ws + 8704;
    float* pI  = pF + 131072;
    float* pO  = pI + 131072;

    __shared__ float smem[2][4][1024];   // parity-buffered raw-state exchange (+ proj scratch)

    // ---- register-resident weight rows (issued early; latency overlaps proj) ----
    float4 wfr[4], wir[4], wgr[4], wor[4], wpr[4];
    {
        const float4* rf = (const float4*)(Wf + (size_t)hrow * 1024);
        const float4* ri = (const float4*)(Wi + (size_t)hrow * 1024);
        const float4* rg = (const float4*)(Wg + (size_t)hrow * 1024);
        const float4* ro = (const float4*)(Wo + (size_t)hrow * 1024);
        const float4* rp = (const float4*)(Wp + (size_t)hrow * 1024);
        #pragma unroll
        for (int q = 0; q < 4; ++q) {
            const int k4 = lane + 64 * q;
            wfr[q] = rf[k4]; wir[q] = ri[k4]; wgr[q] = rg[k4];
            wor[q] = ro[k4]; wpr[q] = rp[k4];
        }
    }
    const float bfv = bf[hrow], biv = bi[hrow], bgv = bg[hrow], bov = bo[hrow], bpv = bp[hrow];

    // ================= Phase 1: projections =================
    {
        float* sF = &smem[0][0][0];     // 512
        float* sI = &smem[0][0][512];   // 512
        float* sO = &smem[0][1][0];     // 512
        sF[t] = tF[t]; sF[t + 256] = tF[t + 256];
        sI[t] = tI[t]; sI[t + 256] = tI[t + 256];
        sO[t] = tO[t]; sO[t + 256] = tO[t + 256];
        __syncthreads();

        const int bd = blk >> 1;
        const int h0 = (blk & 1) * 512;
        const int s  = t & 127;          // float4 slot within the 512-wide half
        const int g  = t >> 7;           // l-parity group
        const float4* tr = (const float4*)trans + (size_t)bd * 512 * 256 + (h0 >> 2) + s;

        float4 aF = make_float4(0.f,0.f,0.f,0.f);
        float4 aI = make_float4(0.f,0.f,0.f,0.f);
        float4 aO = make_float4(0.f,0.f,0.f,0.f);
        #pragma unroll 8
        for (int li = 0; li < 256; ++li) {
            const int l = g + 2 * li;
            float4 v = tr[(size_t)l * 256];
            const float wf = sF[l], wi = sI[l], wo = sO[l];
            aF.x = fmaf(v.x, wf, aF.x); aF.y = fmaf(v.y, wf, aF.y);
            aF.z = fmaf(v.z, wf, aF.z); aF.w = fmaf(v.w, wf, aF.w);
            aI.x = fmaf(v.x, wi, aI.x); aI.y = fmaf(v.y, wi, aI.y);
            aI.z = fmaf(v.z, wi, aI.z); aI.w = fmaf(v.w, wi, aI.w);
            aO.x = fmaf(v.x, wo, aO.x); aO.y = fmaf(v.y, wo, aO.y);
            aO.z = fmaf(v.z, wo, aO.z); aO.w = fmaf(v.w, wo, aO.w);
        }
        float4* cmb = (float4*)&smem[0][2][0];   // 384 float4
        if (g == 1) { cmb[s] = aF; cmb[128 + s] = aI; cmb[256 + s] = aO; }
        __syncthreads();
        if (g == 0) {
            const float4 bF = cmb[s], bI = cmb[128 + s], bO = cmb[256 + s];
            aF.x += bF.x; aF.y += bF.y; aF.z += bF.z; aF.w += bF.w;
            aI.x += bI.x; aI.y += bI.y; aI.z += bI.z; aI.w += bI.w;
            aO.x += bO.x; aO.y += bO.y; aO.z += bO.z; aO.w += bO.w;
            const int base = bd * 1024 + h0 + 4 * s;
            astf(&pF[base+0], aF.x); astf(&pF[base+1], aF.y);
            astf(&pF[base+2], aF.z); astf(&pF[base+3], aF.w);
            astf(&pI[base+0], aI.x); astf(&pI[base+1], aI.y);
            astf(&pI[base+2], aI.z); astf(&pI[base+3], aI.w);
            astf(&pO[base+0], aO.x); astf(&pO[base+1], aO.y);
            astf(&pO[base+2], aO.z); astf(&pO[base+3], aO.w);
        }
    }
    __syncthreads();                     // drain proj stores (vmcnt(0) before s_barrier)
    if (t == 0) astu(&flags[blk], 1u);

    // ---- fold LN affine into weights; per-row scalars (overlaps other blocks' proj) ----
    float sfv, siv, sgv, sov, spv, bfb, bib, bgb, bob, bpb;
    {
        float4 gh4[4], bh4[4], gc4[4], bc4[4];
        const float4* Gh = (const float4*)h_gamma;
        const float4* Bh = (const float4*)h_beta;
        const float4* Gc = (const float4*)c_gamma;
        const float4* Bc = (const float4*)c_beta;
        #pragma unroll
        for (int q = 0; q < 4; ++q) {
            const int k4 = lane + 64 * q;
            gh4[q] = Gh[k4]; bh4[q] = Bh[k4]; gc4[q] = Gc[k4]; bc4[q] = Bc[k4];
        }
        bfb = bib = bgb = bob = bpb = 0.f;
        #pragma unroll
        for (int q = 0; q < 4; ++q) {
            bfb += wfr[q].x*bh4[q].x + wfr[q].y*bh4[q].y + wfr[q].z*bh4[q].z + wfr[q].w*bh4[q].w;
            bib += wir[q].x*bh4[q].x + wir[q].y*bh4[q].y + wir[q].z*bh4[q].z + wir[q].w*bh4[q].w;
            bgb += wgr[q].x*bh4[q].x + wgr[q].y*bh4[q].y + wgr[q].z*bh4[q].z + wgr[q].w*bh4[q].w;
            bob += wor[q].x*bh4[q].x + wor[q].y*bh4[q].y + wor[q].z*bh4[q].z + wor[q].w*bh4[q].w;
            bpb += wpr[q].x*bc4[q].x + wpr[q].y*bc4[q].y + wpr[q].z*bc4[q].z + wpr[q].w*bc4[q].w;
        }
        #pragma unroll
        for (int q = 0; q < 4; ++q) {
            wfr[q].x *= gh4[q].x; wfr[q].y *= gh4[q].y; wfr[q].z *= gh4[q].z; wfr[q].w *= gh4[q].w;
            wir[q].x *= gh4[q].x; wir[q].y *= gh4[q].y; wir[q].z *= gh4[q].z; wir[q].w *= gh4[q].w;
            wgr[q].x *= gh4[q].x; wgr[q].y *= gh4[q].y; wgr[q].z *= gh4[q].z; wgr[q].w *= gh4[q].w;
            wor[q].x *= gh4[q].x; wor[q].y *= gh4[q].y; wor[q].z *= gh4[q].z; wor[q].w *= gh4[q].w;
            wpr[q].x *= gc4[q].x; wpr[q].y *= gc4[q].y; wpr[q].z *= gc4[q].z; wpr[q].w *= gc4[q].w;
        }
        sfv = siv = sgv = sov = spv = 0.f;
        #pragma unroll
        for (int q = 0; q < 4; ++q) {
            sfv += wfr[q].x + wfr[q].y + wfr[q].z + wfr[q].w;
            siv += wir[q].x + wir[q].y + wir[q].z + wir[q].w;
            sgv += wgr[q].x + wgr[q].y + wgr[q].z + wgr[q].w;
            sov += wor[q].x + wor[q].y + wor[q].z + wor[q].w;
            spv += wpr[q].x + wpr[q].y + wpr[q].z + wpr[q].w;
        }
        #pragma unroll
        for (int off = 32; off; off >>= 1) {
            sfv += __shfl_xor(sfv, off); siv += __shfl_xor(siv, off);
            sgv += __shfl_xor(sgv, off); sov += __shfl_xor(sov, off);
            spv += __shfl_xor(spv, off);
            bfb += __shfl_xor(bfb, off); bib += __shfl_xor(bib, off);
            bgb += __shfl_xor(bgb, off); bob += __shfl_xor(bob, off);
            bpb += __shfl_xor(bpb, off);
        }
    }

    // ---- phase-1 completion (aggregator + replicated release).
    //      MUST precede the first proj prefetch (round-2 lesson).
    if (blk == 0) {
        if (wv == 0) {
            for (;;) {
                const unsigned a0 = aldu(&flags[lane]);
                const unsigned a1 = aldu(&flags[lane + 64]);
                const unsigned a2 = aldu(&flags[lane + 128]);
                const unsigned a3 = aldu(&flags[lane + 192]);
                const int ok = (a0 >= 1u) && (a1 >= 1u) && (a2 >= 1u) && (a3 >= 1u);
                if (__all(ok)) break;
                __builtin_amdgcn_s_sleep(1);
            }
            if (lane < 16) astu(&rel[lane * 16], 1u);
        }
    } else if (t == 0) {
        while (aldu(&rel[(blk & 15) * 16]) < 1u) __builtin_amdgcn_s_sleep(2);
    }
    __syncthreads();

    // ================= Phase 2: recurrence =================
    float c_prev = 0.f, h_prev = 0.f;    // lane<2: own row's state, register-resident

    for (int d = 0; d < 64; ++d) {
        const int par = d & 1;
        const float* cc = stC + par * 2048;
        const float* hc = stH + par * 2048;
        float* cn = stC + (par ^ 1) * 2048;
        float* hn = stH + (par ^ 1) * 2048;
        float (*sm)[1024] = smem[par];

        // prefetch this step's projection scalars + mask (latency hides under poll)
        float pfv = 0.f, piv = 0.f, pov = 0.f;
        int mv = 1;
        if (lane < 2) {
            const int pidx = (lane * 64 + d) * 1024 + hrow;
            pfv = aldf(&pF[pidx]); piv = aldf(&pI[pidx]); pov = aldf(&pO[pidx]);
            mv = mask[lane * 64 + d];
        }

        // ---- sync: aggregator detects, consumers poll their private release line ----
        {
            const unsigned tgt = (unsigned)(d + 1);
            if (blk == 0) {
                if (wv == 0) {
                    for (;;) {
                        const unsigned a0 = aldu(&flags[lane]);
                        const unsigned a1 = aldu(&flags[lane + 64]);
                        const unsigned a2 = aldu(&flags[lane + 128]);
                        const unsigned a3 = aldu(&flags[lane + 192]);
                        const int ok = (a0 >= tgt) && (a1 >= tgt) && (a2 >= tgt) && (a3 >= tgt);
                        if (__all(ok)) break;
                        __builtin_amdgcn_s_sleep(1);
                    }
                    if (lane < 16) astu(&rel[lane * 16], tgt);
                }
            } else if (t == 0) {
                while (aldu(&rel[(blk & 15) * 16]) < tgt) __builtin_amdgcn_s_sleep(2);
            }
            __syncthreads();
        }

        // ---- cooperative state read (agent scope) -> raw into smem ----
        float lh0[4], lh1[4], lc0[4], lc1[4];
        #pragma unroll
        for (int j = 0; j < 4; ++j) {
            const int e = t + 256 * j;
            lh0[j] = aldf(hc + e);        lh1[j] = aldf(hc + 1024 + e);
            lc0[j] = aldf(cc + e);        lc1[j] = aldf(cc + 1024 + e);
        }
        #pragma unroll
        for (int j = 0; j < 4; ++j) {
            const int e = t + 256 * j;
            sm[0][e] = lh0[j]; sm[1][e] = lh1[j];
            sm[2][e] = lc0[j]; sm[3][e] = lc1[j];
        }
        __syncthreads();

        // ---- 10 dot products on RAW state + per-wave LN stats (each wave reads the
        //      FULL 1024-vector: k4 = lane + 64q spans all 256 float4s). No red[] exchange.
        float zf0=0,zf1=0,zi0=0,zi1=0,zg0=0,zg1=0,zo0=0,zo1=0,zp0=0,zp1=0;
        float sH0=0,qH0=0,sH1=0,qH1=0,sC0=0,qC0=0,sC1=0,qC1=0;
        #pragma unroll
        for (int q = 0; q < 4; ++q) {
            const int k4 = lane + 64 * q;
            const float4 n0 = ((const float4*)sm[0])[k4];
            const float4 n1 = ((const float4*)sm[1])[k4];
            const float4 m0 = ((const float4*)sm[2])[k4];
            const float4 m1 = ((const float4*)sm[3])[k4];
            zf0 += wfr[q].x*n0.x + wfr[q].y*n0.y + wfr[q].z*n0.z + wfr[q].w*n0.w;
            zf1 += wfr[q].x*n1.x + wfr[q].y*n1.y + wfr[q].z*n1.z + wfr[q].w*n1.w;
            zi0 += wir[q].x*n0.x + wir[q].y*n0.y + wir[q].z*n0.z + wir[q].w*n0.w;
            zi1 += wir[q].x*n1.x + wir[q].y*n1.y + wir[q].z*n1.z + wir[q].w*n1.w;
            zg0 += wgr[q].x*n0.x + wgr[q].y*n0.y + wgr[q].z*n0.z + wgr[q].w*n0.w;
            zg1 += wgr[q].x*n1.x + wgr[q].y*n1.y + wgr[q].z*n1.z + wgr[q].w*n1.w;
            zo0 += wor[q].x*n0.x + wor[q].y*n0.y + wor[q].z*n0.z + wor[q].w*n0.w;
            zo1 += wor[q].x*n1.x + wor[q].y*n1.y + wor[q].z*n1.z + wor[q].w*n1.w;
            zp0 += wpr[q].x*m0.x + wpr[q].y*m0.y + wpr[q].z*m0.z + wpr[q].w*m0.w;
            zp1 += wpr[q].x*m1.x + wpr[q].y*m1.y + wpr[q].z*m1.z + wpr[q].w*m1.w;
            sH0 += n0.x + n0.y + n0.z + n0.w;
            qH0 += n0.x*n0.x + n0.y*n0.y + n0.z*n0.z + n0.w*n0.w;
            sH1 += n1.x + n1.y + n1.z + n1.w;
            qH1 += n1.x*n1.x + n1.y*n1.y + n1.z*n1.z + n1.w*n1.w;
            sC0 += m0.x + m0.y + m0.z + m0.w;
            qC0 += m0.x*m0.x + m0.y*m0.y + m0.z*m0.z + m0.w*m0.w;
            sC1 += m1.x + m1.y + m1.z + m1.w;
            qC1 += m1.x*m1.x + m1.y*m1.y + m1.z*m1.z + m1.w*m1.w;
        }
        #pragma unroll
        for (int off = 32; off; off >>= 1) {
            zf0 += __shfl_xor(zf0, off); zf1 += __shfl_xor(zf1, off);
            zi0 += __shfl_xor(zi0, off); zi1 += __shfl_xor(zi1, off);
            zg0 += __shfl_xor(zg0, off); zg1 += __shfl_xor(zg1, off);
            zo0 += __shfl_xor(zo0, off); zo1 += __shfl_xor(zo1, off);
            zp0 += __shfl_xor(zp0, off); zp1 += __shfl_xor(zp1, off);
            sH0 += __shfl_xor(sH0, off); qH0 += __shfl_xor(qH0, off);
            sH1 += __shfl_xor(sH1, off); qH1 += __shfl_xor(qH1, off);
            sC0 += __shfl_xor(sC0, off); qC0 += __shfl_xor(qC0, off);
            sC1 += __shfl_xor(sC1, off); qC1 += __shfl_xor(qC1, off);
        }

        // ---- finalize z (affine correction) + gates: lane 0 -> b=0, lane 1 -> b=1 ----
        if (lane < 2) {
            const int b = lane;
            const float inv = 1.0f / 1024.0f;
            const float mh = (b ? sH1 : sH0) * inv;
            const float qh = (b ? qH1 : qH0) * inv;
            const float rh = rsqrtf(qh - mh * mh + 1e-5f);
            const float mc = (b ? sC1 : sC0) * inv;
            const float qc = (b ? qC1 : qC0) * inv;
            const float rc = rsqrtf(qc - mc * mc + 1e-5f);
            const float zf = rh * ((b ? zf1 : zf0) - mh * sfv) + bfb;
            const float zi = rh * ((b ? zi1 : zi0) - mh * siv) + bib;
            const float zg = rh * ((b ? zg1 : zg0) - mh * sgv) + bgb;
            const float zo = rh * ((b ? zo1 : zo0) - mh * sov) + bob;
            const float zp = rc * ((b ? zp1 : zp0) - mc * spv) + bpb;
            const float f  = sigf(clampf(zf + bfv, -8.f, 8.f) + pfv);
            const float ig = sigf(clampf(zi + biv, -8.f, 8.f) + piv);
            const float g  = clampf(geluf(zg + bgv) + piv, -8.f, 8.f);
            const float o  = sigf(clampf(zo + bov, -8.f, 8.f) + pov);
            const float hp = clampf(geluf(zp + bpv), -8.f, 8.f);
            float c2 = c_prev * f + ig * g;
            float h2 = o * hp;
            if (mv == 0) { c2 = c_prev; h2 = h_prev; }
            c2 = clampf(c2, -10.f, 10.f);
            h2 = clampf(h2, -10.f, 10.f);
            c_prev = c2; h_prev = h2;
            if (d == 63) {
                out[b * 1024 + hrow] = h2;
            } else {
                astf(cn + b * 1024 + hrow, c2);
                astf(hn + b * 1024 + hrow, h2);
            }
        }

        if (d == 63) break;
        __syncthreads();                         // drain state stores (vmcnt(0) before s_barrier)
        if (t == 0) astu(&flags[blk], (unsigned)(d + 2));
    }
}

extern "C" void kernel_launch(void* const* d_in, const int* in_sizes, int n_in,
                              void* d_out, int out_size, void* d_ws, size_t ws_size,
                              hipStream_t stream)
{
    const float* trans = (const float*)d_in[0];
    const int*   mask  = (const int*)d_in[1];
    const float* Wf = (const float*)d_in[2];  const float* bf = (const float*)d_in[3];
    const float* Wi = (const float*)d_in[4];  const float* bi = (const float*)d_in[5];
    const float* Wg = (const float*)d_in[6];  const float* bg = (const float*)d_in[7];
    const float* Wo = (const float*)d_in[8];  const float* bo = (const float*)d_in[9];
    const float* Wp = (const float*)d_in[10]; const float* bp = (const float*)d_in[11];
    const float* tF = (const float*)d_in[12];
    const float* tI = (const float*)d_in[13];
    const float* tO = (const float*)d_in[14];
    const float* c_gamma = (const float*)d_in[15];
    const float* c_beta  = (const float*)d_in[16];
    const float* h_gamma = (const float*)d_in[17];
    const float* h_beta  = (const float*)d_in[18];

    float* ws  = (float*)d_ws;
    float* out = (float*)d_out;

    // zero flags + rel + initial c/h state only (35 KB)
    hipMemsetAsync(d_ws, 0, 8704u * sizeof(float), stream);

    void* args[] = { (void*)&trans, (void*)&mask,
                     (void*)&Wf, (void*)&bf, (void*)&Wi, (void*)&bi,
                     (void*)&Wg, (void*)&bg, (void*)&Wo, (void*)&bo,
                     (void*)&Wp, (void*)&bp,
                     (void*)&tF, (void*)&tI, (void*)&tO,
                     (void*)&c_gamma, (void*)&c_beta, (void*)&h_gamma, (void*)&h_beta,
                     (void*)&ws, (void*)&out };
    hipLaunchCooperativeKernel((void*)fused_kernel, dim3(256), dim3(256), args, 0, stream);
}